// Round 6
// baseline (562.653 us; speedup 1.0000x reference)
//
#include <hip/hip_runtime.h>

// VectorQuantizer forward — outputs f32, concatenated:
//   out[0..8388608)        = z_e (STE forward value == z), NHWC order   [PASSES]
//   out[8388608..8519680)  = argmin indices as f32, row (b,c,h) = z_e[b,h,:,c]
//   out[8519680]           = 0.25 * mean((z_q - z)^2)
//
// The reference indices come from an f32 pipeline where d2 = (A - 2B) + C is
// rounded at ulp(A~64)=7.6e-6 per element — we REPLICATE that rounding:
//   A[n] = sequential f32 sum of fl(f_d^2)   (candidate order #1: strict seq)
//   B    = fl((float) exact_f64_dot)         (centroid of any gemm order)
//   C[k] = sequential f32 sum of fl(e_d^2)
//   score = fl(fl(A - 2B) + C), argmin with first-min tie-break.

#define N_Z 8388608   // 32*64*64*64
#define N_IDX 131072  // 32*64*64
#define K_EMB 1024
#define D_EMB 64

__global__ __launch_bounds__(256) void ek2f_kernel(
    const float* __restrict__ emb, float* __restrict__ ek2f) {
  int k = blockIdx.x * 256 + threadIdx.x;   // 4 blocks -> 1024
  const float* row = emb + (size_t)k * D_EMB;
  float s = 0.0f;
  for (int d = 0; d < D_EMB; d++) {
    float e = row[d];
    float sq = e * e;
    asm volatile("" : "+v"(sq));   // block FMA-contraction / reassociation
    s = s + sq;
  }
  ek2f[k] = s;
}

// One block per (b,h): z tile z_e[b,h,:,:] is a contiguous [w=64][c=64] block.
// 256 threads = 16 c-groups (i4 = t>>4, c = 4*i4+ci) x 16 k-lanes (j = t&15,
// k = kt*64 + j + 16*s). Dot in exact f64; score combine in f32.
__global__ __launch_bounds__(256) void vq_main_kernel(
    const float* __restrict__ z, const float* __restrict__ emb,
    const float* __restrict__ ek2g, float* __restrict__ out_idx,
    double* __restrict__ loss_acc) {
  __shared__ double zt[64][64];   // [w][c] 32 KB
  __shared__ double et[64][64];   // [w][k_local] 32 KB
  __shared__ float sk2[K_EMB];    // 4 KB
  __shared__ float sa[64];        // A[c] for this (b,h)
  __shared__ double lred[16];

  const int t = threadIdx.x;
  const int bid = blockIdx.x;     // = b*64 + h
  const int j = t & 15;           // k lane
  const int i4 = t >> 4;          // c group

  // ---- stage z tile (4096 floats) as double, [w][c] ----
  const float4* zt4 = (const float4*)(z + (size_t)bid * 4096);
  #pragma unroll
  for (int q = 0; q < 4; q++) {
    int p = t + q * 256;          // float4 index 0..1023
    float4 v = zt4[p];
    int w = p >> 4;
    int c = (p & 15) * 4;
    zt[w][c + 0] = v.x; zt[w][c + 1] = v.y;
    zt[w][c + 2] = v.z; zt[w][c + 3] = v.w;
  }
  // ---- stage C[k] ----
  #pragma unroll
  for (int q = 0; q < 4; q++) sk2[t + q * 256] = ek2g[t + q * 256];

  __syncthreads();
  // ---- A[c]: strict sequential f32 sum of fl(f_d^2), d = w ascending ----
  if (t < 64) {
    float a = 0.0f;
    for (int w = 0; w < 64; w++) {
      float zf = (float)zt[w][t];          // exact (zt holds f32 values)
      float sq = zf * zf;
      asm volatile("" : "+v"(sq));         // no contraction
      a = a + sq;
    }
    sa[t] = a;
  }

  float best[4];
  int bidx[4];
  #pragma unroll
  for (int ci = 0; ci < 4; ci++) { best[ci] = 3.0e38f; bidx[ci] = 0; }

  for (int kt = 0; kt < 16; kt++) {
    __syncthreads();   // et readers done; also publishes sa on kt==0
    // ---- stage 64 embedding rows, transposed to [w][k], as double ----
    {
      int k = t & 63;
      int w4base = t >> 6;        // 0..3
      #pragma unroll
      for (int q = 0; q < 4; q++) {
        int w4 = w4base + q * 4;  // 0..15
        float4 v = *(const float4*)(emb + ((size_t)(kt * 64 + k)) * 64 + w4 * 4);
        et[w4 * 4 + 0][k] = v.x; et[w4 * 4 + 1][k] = v.y;
        et[w4 * 4 + 2][k] = v.z; et[w4 * 4 + 3][k] = v.w;
      }
    }
    __syncthreads();

    double acc[4][4];
    #pragma unroll
    for (int ci = 0; ci < 4; ci++)
      #pragma unroll
      for (int s = 0; s < 4; s++) acc[ci][s] = 0.0;

    #pragma unroll 4
    for (int w = 0; w < 64; w++) {
      double zr[4], er[4];
      #pragma unroll
      for (int ci = 0; ci < 4; ci++) zr[ci] = zt[w][i4 * 4 + ci];
      #pragma unroll
      for (int s = 0; s < 4; s++) er[s] = et[w][j + 16 * s];
      #pragma unroll
      for (int ci = 0; ci < 4; ci++)
        #pragma unroll
        for (int s = 0; s < 4; s++) acc[ci][s] += zr[ci] * er[s];
    }

    // ---- f32 score replication: fl(fl(A - 2B) + C), ties -> lowest k ----
    #pragma unroll
    for (int s = 0; s < 4; s++) {
      int k = kt * 64 + j + 16 * s;
      float ck = sk2[k];
      #pragma unroll
      for (int ci = 0; ci < 4; ci++) {
        float A = sa[i4 * 4 + ci];
        float Bf = (float)acc[ci][s];       // fl(exact dot)
        float t1 = A - 2.0f * Bf;           // fl(A - 2B) (2B exact)
        float sc = t1 + ck;                 // fl(t1 + C)
        if (sc < best[ci]) { best[ci] = sc; bidx[ci] = k; }  // first-min kept
      }
    }
  }

  // ---- reduce (min, first-index) across the 16 k-lanes of each c-group ----
  #pragma unroll
  for (int ci = 0; ci < 4; ci++) {
    float v = best[ci];
    int ix = bidx[ci];
    #pragma unroll
    for (int m = 8; m; m >>= 1) {
      float ov = __shfl_xor(v, m, 16);
      int oi = __shfl_xor(ix, m, 16);
      if (ov < v || (ov == v && oi < ix)) { v = ov; ix = oi; }
    }
    best[ci] = v; bidx[ci] = ix;
  }

  // ---- write indices as f32 (lane j==0 of each group) ----
  const int b = bid >> 6, h = bid & 63;
  if (j == 0) {
    #pragma unroll
    for (int ci = 0; ci < 4; ci++) {
      int c = i4 * 4 + ci;
      int n = b * 4096 + c * 64 + h;      // (b*C + c)*H + h
      out_idx[n] = (float)bidx[ci];
    }
  }

  // ---- loss: sum (z - e[idx])^2 in f64 ----
  double ls = 0.0;
  #pragma unroll
  for (int ci = 0; ci < 4; ci++) {
    int c = i4 * 4 + ci;
    const float* er = emb + (size_t)bidx[ci] * 64;
    #pragma unroll
    for (int s = 0; s < 4; s++) {
      int w = j + 16 * s;
      double d = zt[w][c] - (double)er[w];
      ls += d * d;
    }
  }
  #pragma unroll
  for (int m = 8; m; m >>= 1) ls += __shfl_xor(ls, m, 16);
  if (j == 0) lred[i4] = ls;
  __syncthreads();
  if (t == 0) {
    double s = 0.0;
    #pragma unroll
    for (int q = 0; q < 16; q++) s += lred[q];
    atomicAdd(loss_acc, s);
  }
}

__global__ void loss_final_kernel(const double* __restrict__ acc,
                                  float* __restrict__ out_loss) {
  *out_loss = (float)(0.25 * (*acc) / (double)N_Z);
}

extern "C" void kernel_launch(void* const* d_in, const int* in_sizes, int n_in,
                              void* d_out, int out_size, void* d_ws, size_t ws_size,
                              hipStream_t stream) {
  const float* z = (const float*)d_in[0];     // [32,64,64,64] NHWC
  const float* emb = (const float*)d_in[1];   // [1024,64]
  float* out = (float*)d_out;

  float* ek2f = (float*)d_ws;                            // 1024 floats
  double* lacc = (double*)((char*)d_ws + 4096);          // 1 double, aligned

  (void)hipMemsetAsync(lacc, 0, sizeof(double), stream);
  // out[0] = z (STE forward value): raw f32 device-to-device copy
  (void)hipMemcpyAsync(out, z, (size_t)N_Z * sizeof(float),
                       hipMemcpyDeviceToDevice, stream);
  ek2f_kernel<<<4, 256, 0, stream>>>(emb, ek2f);
  vq_main_kernel<<<2048, 256, 0, stream>>>(z, emb, ek2f, out + N_Z, lacc);
  loss_final_kernel<<<1, 1, 0, stream>>>(lacc, out + N_Z + N_IDX);
}

// Round 7
// 467.185 us; speedup vs baseline: 1.2043x; 1.2043x over previous
//
#include <hip/hip_runtime.h>

// VectorQuantizer forward — outputs f32, concatenated:
//   out[0..8388608)        = z_e (STE forward value == z), NHWC order
//   out[8388608..8519680)  = argmin indices as f32, row (b,c,h) = z_e[b,h,:,c]
//   out[8519680]           = 0.25 * mean((z_q - z)^2)
//
// Two-phase argmin:
//   Phase A (fast): f32-FMA dots, track per-row min/second-min/argmin.
//   Phase B (rare): rows with min2-min1 <= EPS_GAP re-scanned with the exact
//   reference-matching semantics: B = fl(f64 dot), score = fl(fl(A-2B)+C),
//   first-min tie-break.  A and C are bit-exact sequential f32 sums.

#define N_Z 8388608   // 32*64*64*64
#define N_IDX 131072  // 32*64*64
#define K_EMB 1024
#define D_EMB 64
#define EPS_GAP 7e-5f // rigorous bound 4.2e-5; 1.67x safety

__global__ __launch_bounds__(256) void ek2f_kernel(
    const float* __restrict__ emb, float* __restrict__ ek2f) {
  int k = blockIdx.x * 256 + threadIdx.x;   // 4 blocks -> 1024
  const float* row = emb + (size_t)k * D_EMB;
  float s = 0.0f;
  for (int d = 0; d < D_EMB; d++) {
    float e = row[d];
    float sq = e * e;
    asm volatile("" : "+v"(sq));   // block FMA-contraction / reassociation
    s = s + sq;
  }
  ek2f[k] = s;
}

// One block per (b,h): z tile z_e[b,h,:,:] is a contiguous [w=64][c=64] block.
// 256 threads = 16 c-groups (i4 = t>>4) x 16 k-lanes (j = t&15, k = kt*64+j+16s).
__global__ __launch_bounds__(256) void vq_main_kernel(
    const float* __restrict__ z, const float* __restrict__ emb,
    const float* __restrict__ ek2g, float* __restrict__ out_idx,
    double* __restrict__ loss_acc) {
  __shared__ __align__(16) float zts[64][64];  // [w][c] 16 KB
  __shared__ __align__(16) float et2[64][64];  // [w][(k&15)*4+(k>>4)] 16 KB
  __shared__ float sk2[K_EMB];                 // 4 KB
  __shared__ float sa[64];
  __shared__ int sidx[64];
  __shared__ int sflag[64];
  __shared__ double lred[16];
  __shared__ float wrv[4];
  __shared__ int wri[4];

  const int t = threadIdx.x;
  const int bid = blockIdx.x;     // = b*64 + h
  const int j = t & 15;           // k lane
  const int i4 = t >> 4;          // c group

  // ---- stage z tile (4096 floats) as f32, [w][c] ----
  const float4* zt4 = (const float4*)(z + (size_t)bid * 4096);
  #pragma unroll
  for (int q = 0; q < 4; q++) {
    int p = t + q * 256;          // float4 index 0..1023
    float4 v = zt4[p];
    int w = p >> 4;
    int c = (p & 15) * 4;
    *(float4*)&zts[w][c] = v;
  }
  #pragma unroll
  for (int q = 0; q < 4; q++) sk2[t + q * 256] = ek2g[t + q * 256];
  __syncthreads();

  // ---- A[c]: strict sequential f32 sum of fl(z_d^2) (bit-exact, as R6) ----
  if (t < 64) {
    float a = 0.0f;
    for (int w = 0; w < 64; w++) {
      float zf = zts[w][t];
      float sq = zf * zf;
      asm volatile("" : "+v"(sq));
      a = a + sq;
    }
    sa[t] = a;
  }
  __syncthreads();

  float A_[4];
  #pragma unroll
  for (int ci = 0; ci < 4; ci++) A_[ci] = sa[i4 * 4 + ci];

  float m1[4], m2[4];
  int i1[4];
  #pragma unroll
  for (int ci = 0; ci < 4; ci++) { m1[ci] = 3.0e38f; m2[ci] = 3.0e38f; i1[ci] = 0; }

  for (int kt = 0; kt < 16; kt++) {
    __syncthreads();              // previous tile's readers done
    // ---- stage 64 embedding rows: et2[w][(k&15)*4+(k>>4)] ----
    {
      int k = t & 63;
      int w4b = t >> 6;           // 0..3
      int col = (k & 15) * 4 + (k >> 4);
      #pragma unroll
      for (int q = 0; q < 4; q++) {
        int w4 = w4b + q * 4;     // 0..15
        float4 v = *(const float4*)(emb + (size_t)(kt * 64 + k) * 64 + w4 * 4);
        et2[w4 * 4 + 0][col] = v.x; et2[w4 * 4 + 1][col] = v.y;
        et2[w4 * 4 + 2][col] = v.z; et2[w4 * 4 + 3][col] = v.w;
      }
    }
    __syncthreads();

    float acc[4][4];
    #pragma unroll
    for (int ci = 0; ci < 4; ci++)
      #pragma unroll
      for (int s = 0; s < 4; s++) acc[ci][s] = 0.0f;

    #pragma unroll 8
    for (int w = 0; w < 64; w++) {
      float4 zr = *(const float4*)&zts[w][i4 * 4];   // broadcast, conflict-free
      float4 er = *(const float4*)&et2[w][j * 4];    // 2-way (free)
      acc[0][0] += zr.x * er.x; acc[0][1] += zr.x * er.y;
      acc[0][2] += zr.x * er.z; acc[0][3] += zr.x * er.w;
      acc[1][0] += zr.y * er.x; acc[1][1] += zr.y * er.y;
      acc[1][2] += zr.y * er.z; acc[1][3] += zr.y * er.w;
      acc[2][0] += zr.z * er.x; acc[2][1] += zr.z * er.y;
      acc[2][2] += zr.z * er.z; acc[2][3] += zr.z * er.w;
      acc[3][0] += zr.w * er.x; acc[3][1] += zr.w * er.y;
      acc[3][2] += zr.w * er.z; acc[3][3] += zr.w * er.w;
    }

    // ---- approx scores; track min / second-min / first-argmin ----
    #pragma unroll
    for (int s = 0; s < 4; s++) {
      int k = kt * 64 + j + 16 * s;
      float ck = sk2[k];
      #pragma unroll
      for (int ci = 0; ci < 4; ci++) {
        float sc = fmaf(-2.0f, acc[ci][s], A_[ci]) + ck;
        if (sc < m1[ci]) { m2[ci] = m1[ci]; m1[ci] = sc; i1[ci] = k; }
        else             { m2[ci] = fminf(m2[ci], sc); }   // sc==m1 -> m2=m1 (flag)
      }
    }
  }

  // ---- 16-lane top-2 lex merge per c ----
  #pragma unroll
  for (int ci = 0; ci < 4; ci++) {
    float v1 = m1[ci], v2 = m2[ci];
    int ix = i1[ci];
    #pragma unroll
    for (int m = 8; m; m >>= 1) {
      float ov1 = __shfl_xor(v1, m, 16);
      int oi1 = __shfl_xor(ix, m, 16);
      float ov2 = __shfl_xor(v2, m, 16);
      if (ov1 < v1)      { v2 = fminf(v1, ov2); v1 = ov1; ix = oi1; }
      else if (ov1 > v1) { v2 = fminf(v2, ov1); }
      else               { v2 = v1; ix = min(ix, oi1); }   // tie -> force flag
    }
    m1[ci] = v1; m2[ci] = v2; i1[ci] = ix;
  }
  if (j == 0) {
    #pragma unroll
    for (int ci = 0; ci < 4; ci++) {
      int c = i4 * 4 + ci;
      sidx[c] = i1[ci];
      sflag[c] = (m2[ci] - m1[ci] <= EPS_GAP) ? 1 : 0;
    }
  }
  __syncthreads();

  // ---- Phase B: exact re-scan of flagged rows (rare, ~2%) ----
  for (int c = 0; c < 64; c++) {
    if (!sflag[c]) continue;                 // uniform
    float A = sa[c];
    float lm = 3.0e38f;
    int li = 0;
    #pragma unroll
    for (int r = 0; r < 4; r++) {
      int k = t + 256 * r;
      double B = 0.0;
      const float4* e4 = (const float4*)(emb + (size_t)k * 64);
      for (int w4 = 0; w4 < 16; w4++) {
        float4 e = e4[w4];
        B += (double)zts[w4 * 4 + 0][c] * (double)e.x;
        B += (double)zts[w4 * 4 + 1][c] * (double)e.y;
        B += (double)zts[w4 * 4 + 2][c] * (double)e.z;
        B += (double)zts[w4 * 4 + 3][c] * (double)e.w;
      }
      float Bf = (float)B;
      float t1 = A - 2.0f * Bf;              // 2*Bf exact -> single rounding
      float sc = t1 + sk2[k];
      if (sc < lm) { lm = sc; li = k; }      // k ascending -> first-min kept
    }
    #pragma unroll
    for (int m = 32; m; m >>= 1) {
      float ov = __shfl_xor(lm, m);
      int oi = __shfl_xor(li, m);
      if (ov < lm || (ov == lm && oi < li)) { lm = ov; li = oi; }
    }
    int wid = t >> 6;
    if ((t & 63) == 0) { wrv[wid] = lm; wri[wid] = li; }
    __syncthreads();
    if (t == 0) {
      float bv = wrv[0]; int bi = wri[0];
      #pragma unroll
      for (int q = 1; q < 4; q++) {
        if (wrv[q] < bv || (wrv[q] == bv && wri[q] < bi)) { bv = wrv[q]; bi = wri[q]; }
      }
      sidx[c] = bi;
    }
    __syncthreads();
  }
  __syncthreads();

  // ---- write indices ----
  const int b = bid >> 6, h = bid & 63;
  if (t < 64) out_idx[(size_t)b * 4096 + t * 64 + h] = (float)sidx[t];

  // ---- loss: sum (z - e[idx])^2 in f64 ----
  double ls = 0.0;
  #pragma unroll
  for (int ci = 0; ci < 4; ci++) {
    int c = i4 * 4 + ci;
    const float* er = emb + (size_t)sidx[c] * 64;
    #pragma unroll
    for (int s = 0; s < 4; s++) {
      int w = j + 16 * s;
      double d = (double)zts[w][c] - (double)er[w];
      ls += d * d;
    }
  }
  #pragma unroll
  for (int m = 8; m; m >>= 1) ls += __shfl_xor(ls, m, 16);
  if (j == 0) lred[i4] = ls;
  __syncthreads();
  if (t == 0) {
    double s = 0.0;
    #pragma unroll
    for (int q = 0; q < 16; q++) s += lred[q];
    atomicAdd(loss_acc, s);
  }
}

__global__ void loss_final_kernel(const double* __restrict__ acc,
                                  float* __restrict__ out_loss) {
  *out_loss = (float)(0.25 * (*acc) / (double)N_Z);
}

extern "C" void kernel_launch(void* const* d_in, const int* in_sizes, int n_in,
                              void* d_out, int out_size, void* d_ws, size_t ws_size,
                              hipStream_t stream) {
  const float* z = (const float*)d_in[0];     // [32,64,64,64] NHWC
  const float* emb = (const float*)d_in[1];   // [1024,64]
  float* out = (float*)d_out;

  float* ek2f = (float*)d_ws;                            // 1024 floats
  double* lacc = (double*)((char*)d_ws + 4096);          // 1 double, aligned

  (void)hipMemsetAsync(lacc, 0, sizeof(double), stream);
  // out[0] = z (STE forward value): raw f32 device-to-device copy
  (void)hipMemcpyAsync(out, z, (size_t)N_Z * sizeof(float),
                       hipMemcpyDeviceToDevice, stream);
  ek2f_kernel<<<4, 256, 0, stream>>>(emb, ek2f);
  vq_main_kernel<<<2048, 256, 0, stream>>>(z, emb, ek2f, out + N_Z, lacc);
  loss_final_kernel<<<1, 1, 0, stream>>>(lacc, out + N_Z + N_IDX);
}